// Round 5
// baseline (179.401 us; speedup 1.0000x reference)
//
#include <hip/hip_runtime.h>

#define T_DIM 1024
#define B_DIM 8
#define IN_DIM 1024
#define OUT_DIM 1024
#define N_MODL 16
#define K_SEL 2

typedef unsigned short ushort_t;
typedef __bf16 bf16x8 __attribute__((ext_vector_type(8)));
typedef float f32x16 __attribute__((ext_vector_type(16)));

__device__ __forceinline__ unsigned int f2bf2(float lo, float hi) {
  union { float f; unsigned int u; } a, b; a.f = lo; b.f = hi;
  unsigned int ra = (a.u + 0x7fffu + ((a.u >> 16) & 1u)) >> 16;
  unsigned int rb = (b.u + 0x7fffu + ((b.u >> 16) & 1u)) >> 16;
  return ra | (rb << 16);
}

__device__ __forceinline__ void async_g2l(const void* g, void* l) {
  __builtin_amdgcn_global_load_lds(
      (const __attribute__((address_space(1))) unsigned int*)g,
      (__attribute__((address_space(3))) unsigned int*)l,
      16, 0, 0);
}

__device__ __forceinline__ int read_sel(const int* __restrict__ s, int g) {
  bool i64 = true;
#pragma unroll
  for (int j = 0; j < 8; ++j) i64 &= (s[2 * j + 1] == 0);
  return i64 ? s[2 * g] : s[g];
}

// Blocks [0,1024): W [16,IN,OUT] f32 -> Wt [16,OUT,IN] bf16, 128x128 tiles,
//   bf16-in-LDS with XOR swizzle, skipping experts not in `selection`.
// Blocks [1024,5120): x [T,B,IN] f32 -> bf16 stream convert (same layout).
__global__ __launch_bounds__(256) void convert_kernel(const float* __restrict__ x,
                                                      const float* __restrict__ w,
                                                      const int* __restrict__ selp,
                                                      ushort_t* __restrict__ xb,
                                                      ushort_t* __restrict__ wt) {
  __shared__ ushort_t tb[128 * 128];   // 32KB
  const int bid = blockIdx.x;
  if (bid >= 1024) {
    const int i = (bid - 1024) * 256 + threadIdx.x;
    const float4* s = (const float4*)x;
    float4 a = s[i * 2], b = s[i * 2 + 1];
    uint4 o;
    o.x = f2bf2(a.x, a.y); o.y = f2bf2(a.z, a.w);
    o.z = f2bf2(b.x, b.y); o.w = f2bf2(b.z, b.w);
    ((uint4*)xb)[i] = o;
    return;
  }
  const int m = bid >> 6;
  bool used = false;
#pragma unroll
  for (int g = 0; g < B_DIM * K_SEL; ++g) used |= (read_sel(selp, g) == m);
  if (!used) return;

  const int i0 = ((bid >> 3) & 7) * 128;
  const int o0 = (bid & 7) * 128;
  const float* src = w + ((size_t)(m * IN_DIM + i0)) * OUT_DIM + o0;

  const int o4 = (threadIdx.x & 31) * 4;
  const int ib = threadIdx.x >> 5;
#pragma unroll
  for (int p = 0; p < 16; ++p) {
    const int i = ib + p * 8;
    float4 v = *(const float4*)(src + (size_t)i * OUT_DIM + o4);
    const int osw = o4 ^ (((i >> 3) & 15) << 2);
    uint2 d2; d2.x = f2bf2(v.x, v.y); d2.y = f2bf2(v.z, v.w);
    *(uint2*)(tb + i * 128 + osw) = d2;
  }
  __syncthreads();

  ushort_t* dst = wt + ((size_t)(m * OUT_DIM + o0)) * IN_DIM + i0;
  const int il = (threadIdx.x & 15) * 8;
  const int ob = threadIdx.x >> 4;
  const int q2 = ((il >> 3) & 15) << 2;
#pragma unroll
  for (int p = 0; p < 8; ++p) {
    const int o = ob + p * 16;
    const int osw = o ^ q2;
    uint4 d;
    unsigned int u[8];
#pragma unroll
    for (int j = 0; j < 8; ++j) u[j] = tb[(il + j) * 128 + osw];
    d.x = u[0] | (u[1] << 16); d.y = u[2] | (u[3] << 16);
    d.z = u[4] | (u[5] << 16); d.w = u[6] | (u[7] << 16);
    *(uint4*)(dst + (size_t)o * IN_DIM + il) = d;
  }
}

// Fused sibling GEMMs per b. 128x128 tile, BK=64, 4 waves x (64x64 per expert)
// via 2x2 of MFMA 32x32x16 (2382 TF pipe vs 2075 for 16x16x32).
// XOR-swizzled LDS chunks: 0 conflicts (8 lanes/bank-group, balanced).
// Grid dim3(8,8,8) — R4's XCD pinning regressed (L2 hotspotting), reverted.
__global__ __launch_bounds__(256, 2) void mlgemm_kernel(const ushort_t* __restrict__ xb,
                                                        const ushort_t* __restrict__ wt,
                                                        const int* __restrict__ selp,
                                                        const float* __restrict__ bias,
                                                        float* __restrict__ out) {
  __shared__ ushort_t As[128 * 64];      // 16KB
  __shared__ ushort_t Bs[2][128 * 64];   // 32KB

  const int b = blockIdx.z;
  const int e0 = read_sel(selp, 2 * b);
  const int e1 = read_sel(selp, 2 * b + 1);

  const ushort_t* A  = xb + (size_t)b * IN_DIM;          // row t at + t*B*IN
  const ushort_t* B0 = wt + (size_t)e0 * OUT_DIM * IN_DIM;
  const ushort_t* B1 = wt + (size_t)e1 * OUT_DIM * IN_DIM;

  const int m0 = blockIdx.y * 128;
  const int n0 = blockIdx.x * 128;

  const int lane = threadIdx.x & 63;
  const int wv = threadIdx.x >> 6;

  // staging: region j = 8 rows x 8 swizzled 16B chunks; lane l -> slot j*64+l
  const int srow = lane >> 3;
  const int sx = (((lane & 7) ^ (srow & 7)) << 3);
  const ushort_t* Ab  = A  + (size_t)(m0 + srow) * (B_DIM * IN_DIM) + sx;
  const ushort_t* Bb0 = B0 + (size_t)(n0 + srow) * IN_DIM + sx;
  const ushort_t* Bb1 = B1 + (size_t)(n0 + srow) * IN_DIM + sx;

  // 32x32x16 fragments: A[m=lane&31][k=h*8+j], h=lane>>5; B same on [n][k].
  // swizzled chunk for k-step s: ((s<<1) ^ h ^ (row&7)); row&7 == r&7.
  const int r32 = lane & 31;
  const int h = lane >> 5;
  const int hb = (h ^ (r32 & 7)) << 3;       // per-lane base element offset
  const int wrow = (wv & 1) * 64;
  const int wcol = (wv >> 1) * 64;
  const ushort_t* Ard  = As    + (wrow + r32) * 64;
  const ushort_t* Brd0 = Bs[0] + (wcol + r32) * 64;
  const ushort_t* Brd1 = Bs[1] + (wcol + r32) * 64;

  f32x16 acc0[2][2] = {};
  f32x16 acc1[2][2] = {};

  for (int k0 = 0; k0 < IN_DIM; k0 += 64) {
#pragma unroll
    for (int c = 0; c < 4; ++c) {
      const int j = wv * 4 + c;                 // 16 regions cover 128 rows
      async_g2l(Ab  + (size_t)(8 * j) * (B_DIM * IN_DIM) + k0, As + j * 512);
      async_g2l(Bb0 + (size_t)(8 * j) * IN_DIM + k0, Bs[0] + j * 512);
      async_g2l(Bb1 + (size_t)(8 * j) * IN_DIM + k0, Bs[1] + j * 512);
    }
    __syncthreads();   // vmcnt(0) drain: staging visible
#pragma unroll
    for (int s = 0; s < 4; ++s) {              // 4 k-steps of 16
      const int co = hb ^ (s << 4);            // ((s<<1)^...)<<3
      bf16x8 af[2], bf0[2], bf1[2];
#pragma unroll
      for (int i = 0; i < 2; ++i) {
        af[i]  = *(const bf16x8*)(Ard  + i * 32 * 64 + co);
        bf0[i] = *(const bf16x8*)(Brd0 + i * 32 * 64 + co);
        bf1[i] = *(const bf16x8*)(Brd1 + i * 32 * 64 + co);
      }
#pragma unroll
      for (int mt = 0; mt < 2; ++mt)
#pragma unroll
        for (int nt = 0; nt < 2; ++nt) {
          acc0[mt][nt] = __builtin_amdgcn_mfma_f32_32x32x16_bf16(af[mt], bf0[nt],
                                                                 acc0[mt][nt], 0, 0, 0);
          acc1[mt][nt] = __builtin_amdgcn_mfma_f32_32x32x16_bf16(af[mt], bf1[nt],
                                                                 acc1[mt][nt], 0, 0, 0);
        }
    }
    __syncthreads();
  }

  // epilogue: C/D map col=lane&31, row=(reg&3)+8*(reg>>2)+4*(lane>>5)
  const int ocol0 = n0 + wcol + r32;
  const float* bp0 = bias + (size_t)e0 * OUT_DIM;
  const float* bp1 = bias + (size_t)e1 * OUT_DIM;
  float bv0[2], bv1[2];
#pragma unroll
  for (int nt = 0; nt < 2; ++nt) {
    bv0[nt] = bp0[ocol0 + nt * 32];
    bv1[nt] = bp1[ocol0 + nt * 32];
  }
  float* C0 = out + (size_t)b * (K_SEL * OUT_DIM);
  float* C1 = C0 + OUT_DIM;
#pragma unroll
  for (int mt = 0; mt < 2; ++mt) {
#pragma unroll
    for (int reg = 0; reg < 16; ++reg) {
      const int row = m0 + wrow + mt * 32 + (reg & 3) + 8 * (reg >> 2) + 4 * h;
      const size_t rowoff = (size_t)row * (B_DIM * K_SEL * OUT_DIM);
#pragma unroll
      for (int nt = 0; nt < 2; ++nt) {
        C0[rowoff + ocol0 + nt * 32] = acc0[mt][nt][reg] + bv0[nt];
        C1[rowoff + ocol0 + nt * 32] = acc1[mt][nt][reg] + bv1[nt];
      }
    }
  }
}

extern "C" void kernel_launch(void* const* d_in, const int* in_sizes, int n_in,
                              void* d_out, int out_size, void* d_ws, size_t ws_size,
                              hipStream_t stream) {
  const float* x    = (const float*)d_in[0];
  const int*   sel  = (const int*)d_in[1];
  const float* w    = (const float*)d_in[2];
  const float* bias = (const float*)d_in[3];
  float* out = (float*)d_out;

  ushort_t* xb = (ushort_t*)d_ws;                                   // 16 MB
  ushort_t* wt = (ushort_t*)((char*)d_ws +
                             (size_t)T_DIM * B_DIM * IN_DIM * 2);   // +32 MB

  convert_kernel<<<dim3(1024 + T_DIM * B_DIM * IN_DIM / 8 / 256), 256, 0, stream>>>(
      x, w, sel, xb, wt);
  mlgemm_kernel<<<dim3(OUT_DIM / 128, T_DIM / 128, B_DIM), 256, 0, stream>>>(
      xb, wt, sel, bias, out);
}

// Round 6
// 176.612 us; speedup vs baseline: 1.0158x; 1.0158x over previous
//
#include <hip/hip_runtime.h>

#define T_DIM 1024
#define B_DIM 8
#define IN_DIM 1024
#define OUT_DIM 1024
#define N_MODL 16
#define K_SEL 2

typedef unsigned short ushort_t;
typedef __bf16 bf16x8 __attribute__((ext_vector_type(8)));
typedef float f32x4 __attribute__((ext_vector_type(4)));

__device__ __forceinline__ unsigned int f2bf2(float lo, float hi) {
  union { float f; unsigned int u; } a, b; a.f = lo; b.f = hi;
  unsigned int ra = (a.u + 0x7fffu + ((a.u >> 16) & 1u)) >> 16;
  unsigned int rb = (b.u + 0x7fffu + ((b.u >> 16) & 1u)) >> 16;
  return ra | (rb << 16);
}

__device__ __forceinline__ void async_g2l(const void* g, void* l) {
  __builtin_amdgcn_global_load_lds(
      (const __attribute__((address_space(1))) unsigned int*)g,
      (__attribute__((address_space(3))) unsigned int*)l,
      16, 0, 0);
}

__device__ __forceinline__ int read_sel(const int* __restrict__ s, int g) {
  bool i64 = true;
#pragma unroll
  for (int j = 0; j < 8; ++j) i64 &= (s[2 * j + 1] == 0);
  return i64 ? s[2 * g] : s[g];
}

// Blocks [0,1024): W [16,IN,OUT] f32 -> Wt [16,OUT,IN] bf16, 128x128 tiles,
//   bf16-in-LDS with XOR swizzle, skipping experts not in `selection`.
// Blocks [1024,5120): x [T,B,IN] f32 -> bf16 stream convert (same layout).
__global__ __launch_bounds__(256) void convert_kernel(const float* __restrict__ x,
                                                      const float* __restrict__ w,
                                                      const int* __restrict__ selp,
                                                      ushort_t* __restrict__ xb,
                                                      ushort_t* __restrict__ wt) {
  __shared__ ushort_t tb[128 * 128];   // 32KB
  const int bid = blockIdx.x;
  if (bid >= 1024) {
    const int i = (bid - 1024) * 256 + threadIdx.x;
    const float4* s = (const float4*)x;
    float4 a = s[i * 2], b = s[i * 2 + 1];
    uint4 o;
    o.x = f2bf2(a.x, a.y); o.y = f2bf2(a.z, a.w);
    o.z = f2bf2(b.x, b.y); o.w = f2bf2(b.z, b.w);
    ((uint4*)xb)[i] = o;
    return;
  }
  const int m = bid >> 6;
  bool used = false;
#pragma unroll
  for (int g = 0; g < B_DIM * K_SEL; ++g) used |= (read_sel(selp, g) == m);
  if (!used) return;

  const int i0 = ((bid >> 3) & 7) * 128;
  const int o0 = (bid & 7) * 128;
  const float* src = w + ((size_t)(m * IN_DIM + i0)) * OUT_DIM + o0;

  const int o4 = (threadIdx.x & 31) * 4;
  const int ib = threadIdx.x >> 5;
#pragma unroll
  for (int p = 0; p < 16; ++p) {
    const int i = ib + p * 8;
    float4 v = *(const float4*)(src + (size_t)i * OUT_DIM + o4);
    const int osw = o4 ^ (((i >> 3) & 15) << 2);
    uint2 d2; d2.x = f2bf2(v.x, v.y); d2.y = f2bf2(v.z, v.w);
    *(uint2*)(tb + i * 128 + osw) = d2;
  }
  __syncthreads();

  ushort_t* dst = wt + ((size_t)(m * OUT_DIM + o0)) * IN_DIM + i0;
  const int il = (threadIdx.x & 15) * 8;
  const int ob = threadIdx.x >> 4;
  const int q2 = ((il >> 3) & 15) << 2;
#pragma unroll
  for (int p = 0; p < 8; ++p) {
    const int o = ob + p * 16;
    const int osw = o ^ q2;
    uint4 d;
    unsigned int u[8];
#pragma unroll
    for (int j = 0; j < 8; ++j) u[j] = tb[(il + j) * 128 + osw];
    d.x = u[0] | (u[1] << 16); d.y = u[2] | (u[3] << 16);
    d.z = u[4] | (u[5] << 16); d.w = u[6] | (u[7] << 16);
    *(uint4*)(dst + (size_t)o * IN_DIM + il) = d;
  }
}

// Fused sibling GEMMs per b. 128m x 64n tile (2 experts), BK=64, grid 1024
// blocks -> 4 blocks/CU (LDS 32KB) for cross-block barrier-drain overlap.
// 16x16x32 MFMA fragments (16-row: 2-way LDS aliasing = free; 32-row frags
// from R5 caused 4-way conflicts and regressed). XOR-swizzled 16B chunks.
__global__ __launch_bounds__(256, 4) void mlgemm_kernel(const ushort_t* __restrict__ xb,
                                                        const ushort_t* __restrict__ wt,
                                                        const int* __restrict__ selp,
                                                        const float* __restrict__ bias,
                                                        float* __restrict__ out) {
  __shared__ ushort_t As[128 * 64];      // 16KB
  __shared__ ushort_t Bs0[64 * 64];      // 8KB
  __shared__ ushort_t Bs1[64 * 64];      // 8KB

  const int b = blockIdx.z;
  const int e0 = read_sel(selp, 2 * b);
  const int e1 = read_sel(selp, 2 * b + 1);

  const ushort_t* A  = xb + (size_t)b * IN_DIM;          // row t at + t*B*IN
  const ushort_t* B0 = wt + (size_t)e0 * OUT_DIM * IN_DIM;
  const ushort_t* B1 = wt + (size_t)e1 * OUT_DIM * IN_DIM;

  const int m0 = blockIdx.y * 128;
  const int n0 = blockIdx.x * 64;

  const int lane = threadIdx.x & 63;
  const int wv = threadIdx.x >> 6;

  // staging: region = 8 rows x 8 swizzled 16B chunks = 1KB; lane l -> slot l
  const int srow = lane >> 3;
  const int sx = (((lane & 7) ^ (srow & 7)) << 3);
  const ushort_t* Ab  = A  + (size_t)(m0 + srow) * (B_DIM * IN_DIM) + sx;
  const ushort_t* Bb0 = B0 + (size_t)(n0 + srow) * IN_DIM + sx;
  const ushort_t* Bb1 = B1 + (size_t)(n0 + srow) * IN_DIM + sx;

  // fragments: A[m=lane&15][k=quad*8+j]; swizzled chunk = quad ^ (row&7) ^ kk/8
  const int frow = lane & 15;
  const int quad = lane >> 4;
  const int cbase = ((quad ^ (frow & 7)) << 3);
  const int mh = (wv & 1) * 64;          // wave m-half of the 128 rows
  const int nh = (wv >> 1) * 32;         // wave n-half of the 64 cols
  const ushort_t* Ard  = As  + (mh + frow) * 64;
  const ushort_t* Brd0 = Bs0 + (nh + frow) * 64;
  const ushort_t* Brd1 = Bs1 + (nh + frow) * 64;

  f32x4 acc0[4][2] = {};
  f32x4 acc1[4][2] = {};

  for (int k0 = 0; k0 < IN_DIM; k0 += 64) {
#pragma unroll
    for (int c = 0; c < 8; ++c) {
      const int j = wv * 8 + c;          // 32 regions: 16 A, 8 B0, 8 B1
      if (j < 16)
        async_g2l(Ab + (size_t)(8 * j) * (B_DIM * IN_DIM) + k0, As + j * 512);
      else if (j < 24)
        async_g2l(Bb0 + (size_t)(8 * (j - 16)) * IN_DIM + k0, Bs0 + (j - 16) * 512);
      else
        async_g2l(Bb1 + (size_t)(8 * (j - 24)) * IN_DIM + k0, Bs1 + (j - 24) * 512);
    }
    __syncthreads();   // vmcnt(0) drain: staging visible
#pragma unroll
    for (int kk = 0; kk < 64; kk += 32) {
      const int coff = cbase ^ kk;
      bf16x8 af[4], b0f[2], b1f[2];
#pragma unroll
      for (int i = 0; i < 4; ++i)
        af[i] = *(const bf16x8*)(Ard + i * 16 * 64 + coff);
#pragma unroll
      for (int i = 0; i < 2; ++i) {
        b0f[i] = *(const bf16x8*)(Brd0 + i * 16 * 64 + coff);
        b1f[i] = *(const bf16x8*)(Brd1 + i * 16 * 64 + coff);
      }
#pragma unroll
      for (int mt = 0; mt < 4; ++mt)
#pragma unroll
        for (int nt = 0; nt < 2; ++nt) {
          acc0[mt][nt] = __builtin_amdgcn_mfma_f32_16x16x32_bf16(af[mt], b0f[nt],
                                                                 acc0[mt][nt], 0, 0, 0);
          acc1[mt][nt] = __builtin_amdgcn_mfma_f32_16x16x32_bf16(af[mt], b1f[nt],
                                                                 acc1[mt][nt], 0, 0, 0);
        }
    }
    __syncthreads();
  }

  // epilogue: C/D map col=lane&15, row=quad*4+reg
  const int orow0 = m0 + mh + quad * 4;
  const int ocol0 = n0 + nh + frow;
  const float* bp0 = bias + (size_t)e0 * OUT_DIM;
  const float* bp1 = bias + (size_t)e1 * OUT_DIM;
  float bv0[2], bv1[2];
#pragma unroll
  for (int nt = 0; nt < 2; ++nt) {
    bv0[nt] = bp0[ocol0 + nt * 16];
    bv1[nt] = bp1[ocol0 + nt * 16];
  }
  float* C0 = out + (size_t)b * (K_SEL * OUT_DIM);
  float* C1 = C0 + OUT_DIM;
#pragma unroll
  for (int mt = 0; mt < 4; ++mt) {
#pragma unroll
    for (int r = 0; r < 4; ++r) {
      const size_t rowoff = (size_t)(orow0 + mt * 16 + r) * (B_DIM * K_SEL * OUT_DIM);
#pragma unroll
      for (int nt = 0; nt < 2; ++nt) {
        C0[rowoff + ocol0 + nt * 16] = acc0[mt][nt][r] + bv0[nt];
        C1[rowoff + ocol0 + nt * 16] = acc1[mt][nt][r] + bv1[nt];
      }
    }
  }
}

extern "C" void kernel_launch(void* const* d_in, const int* in_sizes, int n_in,
                              void* d_out, int out_size, void* d_ws, size_t ws_size,
                              hipStream_t stream) {
  const float* x    = (const float*)d_in[0];
  const int*   sel  = (const int*)d_in[1];
  const float* w    = (const float*)d_in[2];
  const float* bias = (const float*)d_in[3];
  float* out = (float*)d_out;

  ushort_t* xb = (ushort_t*)d_ws;                                   // 16 MB
  ushort_t* wt = (ushort_t*)((char*)d_ws +
                             (size_t)T_DIM * B_DIM * IN_DIM * 2);   // +32 MB

  convert_kernel<<<dim3(1024 + T_DIM * B_DIM * IN_DIM / 8 / 256), 256, 0, stream>>>(
      x, w, sel, xb, wt);
  mlgemm_kernel<<<dim3(OUT_DIM / 64, T_DIM / 128, B_DIM), 256, 0, stream>>>(
      xb, wt, sel, bias, out);
}